// Round 2
// baseline (2152.784 us; speedup 1.0000x reference)
//
#include <hip/hip_runtime.h>
#include <stdint.h>
#include <stddef.h>

#define N_NODES   100000
#define N_EDGES   3200000
#define F_IN      512
#define HIDDEN    16
#define N_CLASSES 32

// ---------------- Threefry-2x32, JAX-compatible (20 rounds) ----------------
__host__ __device__ __forceinline__ uint32_t rotl32(uint32_t x, int r) {
  return (x << r) | (x >> (32 - r));
}

__host__ __device__ __forceinline__ void tf2x32_full(uint32_t k0, uint32_t k1,
                                                     uint32_t x0, uint32_t x1,
                                                     uint32_t* o0, uint32_t* o1) {
  const uint32_t k2 = k0 ^ k1 ^ 0x1BD11BDAu;
  x0 += k0; x1 += k1;
#define TF_R(r) { x0 += x1; x1 = rotl32(x1, (r)); x1 ^= x0; }
  TF_R(13) TF_R(15) TF_R(26) TF_R(6)   x0 += k1; x1 += k2 + 1u;
  TF_R(17) TF_R(29) TF_R(16) TF_R(24)  x0 += k2; x1 += k0 + 2u;
  TF_R(13) TF_R(15) TF_R(26) TF_R(6)   x0 += k0; x1 += k1 + 3u;
  TF_R(17) TF_R(29) TF_R(16) TF_R(24)  x0 += k1; x1 += k2 + 4u;
  TF_R(13) TF_R(15) TF_R(26) TF_R(6)   x0 += k2; x1 += k0 + 5u;
#undef TF_R
  *o0 = x0; *o1 = x1;
}

// JAX partitionable random_bits (bit_width=32): bits = out0 ^ out1 of
// threefry2x32(key; counts_hi=0, counts_lo=flat_index).
// keep element ⟺ uniform < 0.5 ⟺ MSB(bits) == 0.
__device__ __forceinline__ bool keep_bit(uint32_t k0, uint32_t k1, uint32_t ctr) {
  uint32_t o0, o1;
  tf2x32_full(k0, k1, 0u, ctr, &o0, &o1);
  return (int32_t)(o0 ^ o1) >= 0;
}

// ---------------- k1: dropout(X) @ W1 -> H1 [N,16] ----------------
__launch_bounds__(256)
__global__ void gemm1_dropout(const float* __restrict__ X,
                              const float* __restrict__ W1,
                              float* __restrict__ H1,
                              uint32_t kd0, uint32_t kd1) {
  __shared__ float W1s[F_IN][HIDDEN];  // 32 KB
  const int tid = threadIdx.x;
  for (int i = tid; i < (F_IN * HIDDEN) / 4; i += 256)
    ((float4*)W1s)[i] = ((const float4*)W1)[i];
  __syncthreads();

  const int n = blockIdx.x * 256 + tid;
  if (n >= N_NODES) return;

  float acc[HIDDEN];
#pragma unroll
  for (int j = 0; j < HIDDEN; j++) acc[j] = 0.0f;

  const float4* Xrow = (const float4*)(X + (size_t)n * F_IN);
  const uint32_t jbase = (uint32_t)n * F_IN;

  for (int cc = 0; cc < F_IN / 4; cc++) {
    float4 xv = Xrow[cc];
    float xs[4] = {xv.x, xv.y, xv.z, xv.w};
#pragma unroll
    for (int e = 0; e < 4; e++) {
      const int f = cc * 4 + e;
      const float x = keep_bit(kd0, kd1, jbase + (uint32_t)f) ? xs[e] * 2.0f : 0.0f;
      const float* wr = W1s[f];
#pragma unroll
      for (int j = 0; j < HIDDEN; j++) acc[j] += x * wr[j];
    }
  }

  float4* out = (float4*)(H1 + (size_t)n * HIDDEN);
#pragma unroll
  for (int q = 0; q < HIDDEN / 4; q++)
    out[q] = make_float4(acc[q * 4], acc[q * 4 + 1], acc[q * 4 + 2], acc[q * 4 + 3]);
}

// ---------------- k2: H2[d] += w_e * H1[s_e]   (4 lanes per edge) ----------------
__launch_bounds__(256)
__global__ void spmm1(const int* __restrict__ src, const int* __restrict__ dst,
                      const float* __restrict__ w, const float* __restrict__ H1,
                      float* __restrict__ H2) {
  const long long t = (long long)blockIdx.x * 256 + threadIdx.x;
  if (t >= (long long)N_EDGES * 4) return;
  const int e = (int)(t >> 2);
  const int q = (int)(t & 3);
  const int s = src[e];
  const int d = dst[e];
  const float we = w[e];
  const float4 h = ((const float4*)(H1 + (size_t)s * HIDDEN))[q];
  float* o = H2 + (size_t)d * HIDDEN + q * 4;
  unsafeAtomicAdd(o + 0, we * h.x);
  unsafeAtomicAdd(o + 1, we * h.y);
  unsafeAtomicAdd(o + 2, we * h.z);
  unsafeAtomicAdd(o + 3, we * h.w);
}

// ---------------- k3: dropout(relu(H2)) @ W2 -> H3 [N,32] ----------------
__launch_bounds__(256)
__global__ void gemm2_dropout(const float* __restrict__ H2,
                              const float* __restrict__ W2,
                              float* __restrict__ H3,
                              uint32_t kd0, uint32_t kd1) {
  __shared__ float W2s[HIDDEN][N_CLASSES];  // 2 KB
  const int tid = threadIdx.x;
  for (int i = tid; i < (HIDDEN * N_CLASSES) / 4; i += 256)
    ((float4*)W2s)[i] = ((const float4*)W2)[i];
  __syncthreads();

  const int n = blockIdx.x * 256 + tid;
  if (n >= N_NODES) return;

  float acc[N_CLASSES];
#pragma unroll
  for (int j = 0; j < N_CLASSES; j++) acc[j] = 0.0f;

  const float4* hrow = (const float4*)(H2 + (size_t)n * HIDDEN);
  const uint32_t jbase = (uint32_t)n * HIDDEN;

#pragma unroll
  for (int qq = 0; qq < HIDDEN / 4; qq++) {
    float4 hv = hrow[qq];
    float hs[4] = {hv.x, hv.y, hv.z, hv.w};
#pragma unroll
    for (int e = 0; e < 4; e++) {
      const int c = qq * 4 + e;
      float h = fmaxf(hs[e], 0.0f);
      h = keep_bit(kd0, kd1, jbase + (uint32_t)c) ? h * 2.0f : 0.0f;
      const float* wr = W2s[c];
#pragma unroll
      for (int j = 0; j < N_CLASSES; j++) acc[j] += h * wr[j];
    }
  }

  float4* out = (float4*)(H3 + (size_t)n * N_CLASSES);
#pragma unroll
  for (int q = 0; q < N_CLASSES / 4; q++)
    out[q] = make_float4(acc[q * 4], acc[q * 4 + 1], acc[q * 4 + 2], acc[q * 4 + 3]);
}

// ---------------- k4: OUT[d] += w_e * H3[s_e]   (8 lanes per edge) ----------------
__launch_bounds__(256)
__global__ void spmm2(const int* __restrict__ src, const int* __restrict__ dst,
                      const float* __restrict__ w, const float* __restrict__ H3,
                      float* __restrict__ O) {
  const long long t = (long long)blockIdx.x * 256 + threadIdx.x;
  if (t >= (long long)N_EDGES * 8) return;
  const int e = (int)(t >> 3);
  const int q = (int)(t & 7);
  const int s = src[e];
  const int d = dst[e];
  const float we = w[e];
  const float4 h = ((const float4*)(H3 + (size_t)s * N_CLASSES))[q];
  float* o = O + (size_t)d * N_CLASSES + q * 4;
  unsafeAtomicAdd(o + 0, we * h.x);
  unsafeAtomicAdd(o + 1, we * h.y);
  unsafeAtomicAdd(o + 2, we * h.z);
  unsafeAtomicAdd(o + 3, we * h.w);
}

// ---------------- k5: row softmax over 32 classes, in place ----------------
__launch_bounds__(256)
__global__ void softmax_rows(float* __restrict__ O) {
  const int n = blockIdx.x * 256 + threadIdx.x;
  if (n >= N_NODES) return;
  float4* row = (float4*)(O + (size_t)n * N_CLASSES);
  float v[N_CLASSES];
#pragma unroll
  for (int q = 0; q < N_CLASSES / 4; q++) {
    float4 t = row[q];
    v[q * 4 + 0] = t.x; v[q * 4 + 1] = t.y; v[q * 4 + 2] = t.z; v[q * 4 + 3] = t.w;
  }
  float m = v[0];
#pragma unroll
  for (int j = 1; j < N_CLASSES; j++) m = fmaxf(m, v[j]);
  float s = 0.0f;
#pragma unroll
  for (int j = 0; j < N_CLASSES; j++) { v[j] = __expf(v[j] - m); s += v[j]; }
  const float inv = 1.0f / s;
#pragma unroll
  for (int q = 0; q < N_CLASSES / 4; q++)
    row[q] = make_float4(v[q * 4] * inv, v[q * 4 + 1] * inv,
                         v[q * 4 + 2] * inv, v[q * 4 + 3] * inv);
}

// ---------------- host ----------------
extern "C" void kernel_launch(void* const* d_in, const int* in_sizes, int n_in,
                              void* d_out, int out_size, void* d_ws, size_t ws_size,
                              hipStream_t stream) {
  const float* X    = (const float*)d_in[0];
  const int*   esrc = (const int*)d_in[1];
  const int*   edst = (const int*)d_in[2];
  const float* ew   = (const float*)d_in[3];
  const float* W1   = (const float*)d_in[4];
  const float* W2   = (const float*)d_in[5];
  float* out = (float*)d_out;

  // workspace layout: H1 [N,16] | H2 [N,16] | H3 [N,32]  = 25.6 MB
  float* H1 = (float*)d_ws;
  float* H2 = H1 + (size_t)N_NODES * HIDDEN;
  float* H3 = H2 + (size_t)N_NODES * HIDDEN;

  // JAX: key = random.key(42); kd1, kd2 = random.split(key)
  // partitionable split: kd_i = full 64-bit output of threefry2x32((0,42); 0, i)
  uint32_t kd1_0, kd1_1, kd2_0, kd2_1;
  tf2x32_full(0u, 42u, 0u, 0u, &kd1_0, &kd1_1);
  tf2x32_full(0u, 42u, 0u, 1u, &kd2_0, &kd2_1);

  hipMemsetAsync(H2, 0, (size_t)N_NODES * HIDDEN * sizeof(float), stream);
  hipMemsetAsync(out, 0, (size_t)out_size * sizeof(float), stream);

  const int nb_nodes = (N_NODES + 255) / 256;
  gemm1_dropout<<<nb_nodes, 256, 0, stream>>>(X, W1, H1, kd1_0, kd1_1);
  spmm1<<<(N_EDGES * 4) / 256, 256, 0, stream>>>(esrc, edst, ew, H1, H2);
  gemm2_dropout<<<nb_nodes, 256, 0, stream>>>(H2, W2, H3, kd2_0, kd2_1);
  spmm2<<<(N_EDGES * 8) / 256, 256, 0, stream>>>(esrc, edst, ew, H3, out);
  softmax_rows<<<nb_nodes, 256, 0, stream>>>(out);
}

// Round 3
// 807.913 us; speedup vs baseline: 2.6646x; 2.6646x over previous
//
#include <hip/hip_runtime.h>
#include <stdint.h>
#include <stddef.h>

#define N_NODES   100000
#define N_EDGES   3200000
#define F_IN      512
#define HIDDEN    16
#define N_CLASSES 32

// ---------------- Threefry-2x32, JAX-compatible (20 rounds) ----------------
__host__ __device__ __forceinline__ uint32_t rotl32(uint32_t x, int r) {
  return (x << r) | (x >> (32 - r));
}

__host__ __device__ __forceinline__ void tf2x32_full(uint32_t k0, uint32_t k1,
                                                     uint32_t x0, uint32_t x1,
                                                     uint32_t* o0, uint32_t* o1) {
  const uint32_t k2 = k0 ^ k1 ^ 0x1BD11BDAu;
  x0 += k0; x1 += k1;
#define TF_R(r) { x0 += x1; x1 = rotl32(x1, (r)); x1 ^= x0; }
  TF_R(13) TF_R(15) TF_R(26) TF_R(6)   x0 += k1; x1 += k2 + 1u;
  TF_R(17) TF_R(29) TF_R(16) TF_R(24)  x0 += k2; x1 += k0 + 2u;
  TF_R(13) TF_R(15) TF_R(26) TF_R(6)   x0 += k0; x1 += k1 + 3u;
  TF_R(17) TF_R(29) TF_R(16) TF_R(24)  x0 += k1; x1 += k2 + 4u;
  TF_R(13) TF_R(15) TF_R(26) TF_R(6)   x0 += k2; x1 += k0 + 5u;
#undef TF_R
  *o0 = x0; *o1 = x1;
}

// JAX partitionable random_bits(32): bits = out0 ^ out1 of tf(key; 0, idx).
// keep ⟺ uniform < 0.5 ⟺ MSB(bits)==0.
__device__ __forceinline__ bool keep_bit(uint32_t k0, uint32_t k1, uint32_t ctr) {
  uint32_t o0, o1;
  tf2x32_full(k0, k1, 0u, ctr, &o0, &o1);
  return (int32_t)(o0 ^ o1) >= 0;
}

// ---------------- k1: dropout(X) @ W1 -> H1 [N,16] ----------------
__launch_bounds__(256)
__global__ void gemm1_dropout(const float* __restrict__ X,
                              const float* __restrict__ W1,
                              float* __restrict__ H1,
                              uint32_t kd0, uint32_t kd1) {
  __shared__ float W1s[F_IN][HIDDEN];  // 32 KB
  const int tid = threadIdx.x;
  for (int i = tid; i < (F_IN * HIDDEN) / 4; i += 256)
    ((float4*)W1s)[i] = ((const float4*)W1)[i];
  __syncthreads();

  const int n = blockIdx.x * 256 + tid;
  if (n >= N_NODES) return;

  float acc[HIDDEN];
#pragma unroll
  for (int j = 0; j < HIDDEN; j++) acc[j] = 0.0f;

  const float4* Xrow = (const float4*)(X + (size_t)n * F_IN);
  const uint32_t jbase = (uint32_t)n * F_IN;

  for (int cc = 0; cc < F_IN / 4; cc++) {
    float4 xv = Xrow[cc];
    float xs[4] = {xv.x, xv.y, xv.z, xv.w};
#pragma unroll
    for (int e = 0; e < 4; e++) {
      const int f = cc * 4 + e;
      const float x = keep_bit(kd0, kd1, jbase + (uint32_t)f) ? xs[e] * 2.0f : 0.0f;
      const float* wr = W1s[f];
#pragma unroll
      for (int j = 0; j < HIDDEN; j++) acc[j] += x * wr[j];
    }
  }

  float4* out = (float4*)(H1 + (size_t)n * HIDDEN);
#pragma unroll
  for (int q = 0; q < HIDDEN / 4; q++)
    out[q] = make_float4(acc[q * 4], acc[q * 4 + 1], acc[q * 4 + 2], acc[q * 4 + 3]);
}

// ---------------- k3: dropout(relu(H2)) @ W2 -> H3 [N,32] ----------------
__launch_bounds__(256)
__global__ void gemm2_dropout(const float* __restrict__ H2,
                              const float* __restrict__ W2,
                              float* __restrict__ H3,
                              uint32_t kd0, uint32_t kd1) {
  __shared__ float W2s[HIDDEN][N_CLASSES];  // 2 KB
  const int tid = threadIdx.x;
  for (int i = tid; i < (HIDDEN * N_CLASSES) / 4; i += 256)
    ((float4*)W2s)[i] = ((const float4*)W2)[i];
  __syncthreads();

  const int n = blockIdx.x * 256 + tid;
  if (n >= N_NODES) return;

  float acc[N_CLASSES];
#pragma unroll
  for (int j = 0; j < N_CLASSES; j++) acc[j] = 0.0f;

  const float4* hrow = (const float4*)(H2 + (size_t)n * HIDDEN);
  const uint32_t jbase = (uint32_t)n * HIDDEN;

#pragma unroll
  for (int qq = 0; qq < HIDDEN / 4; qq++) {
    float4 hv = hrow[qq];
    float hs[4] = {hv.x, hv.y, hv.z, hv.w};
#pragma unroll
    for (int e = 0; e < 4; e++) {
      const int c = qq * 4 + e;
      float h = fmaxf(hs[e], 0.0f);
      h = keep_bit(kd0, kd1, jbase + (uint32_t)c) ? h * 2.0f : 0.0f;
      const float* wr = W2s[c];
#pragma unroll
      for (int j = 0; j < N_CLASSES; j++) acc[j] += h * wr[j];
    }
  }

  float4* out = (float4*)(H3 + (size_t)n * N_CLASSES);
#pragma unroll
  for (int q = 0; q < N_CLASSES / 4; q++)
    out[q] = make_float4(acc[q * 4], acc[q * 4 + 1], acc[q * 4 + 2], acc[q * 4 + 3]);
}

// ================= CSR-by-dst build =================
__launch_bounds__(256)
__global__ void hist_dst(const int* __restrict__ dst, int* __restrict__ deg) {
  const int e = blockIdx.x * 256 + threadIdx.x;
  if (e < N_EDGES) atomicAdd(&deg[dst[e]], 1);
}

// block-level exclusive scan over 2048 elements/block
__launch_bounds__(256)
__global__ void scan1(const int* __restrict__ deg, int* __restrict__ row_ptr,
                      int* __restrict__ bsum) {
  __shared__ int s[256];
  const int tid = threadIdx.x;
  const int base = blockIdx.x * 2048 + tid * 8;
  int loc[8];
  int tsum = 0;
#pragma unroll
  for (int i = 0; i < 8; i++) {
    const int idx = base + i;
    const int v = (idx < N_NODES) ? deg[idx] : 0;
    loc[i] = tsum; tsum += v;
  }
  s[tid] = tsum;
  __syncthreads();
  for (int off = 1; off < 256; off <<= 1) {
    const int t = (tid >= off) ? s[tid - off] : 0;
    __syncthreads();
    s[tid] += t;
    __syncthreads();
  }
  const int excl = (tid > 0) ? s[tid - 1] : 0;
#pragma unroll
  for (int i = 0; i < 8; i++) {
    const int idx = base + i;
    if (idx < N_NODES) row_ptr[idx] = excl + loc[i];
  }
  if (tid == 255) bsum[blockIdx.x] = s[255];
}

// scan block partials (nb <= 64), one wave
__global__ void scan2(const int* __restrict__ bsum, int* __restrict__ bexcl, int nb) {
  const int lane = threadIdx.x;
  int v = (lane < nb) ? bsum[lane] : 0;
  for (int off = 1; off < 64; off <<= 1) {
    const int t = __shfl_up(v, off);
    if (lane >= off) v += t;
  }
  const int e = __shfl_up(v, 1);
  if (lane < nb) bexcl[lane] = (lane == 0) ? 0 : e;
}

__launch_bounds__(256)
__global__ void scan3_cursor(int* __restrict__ row_ptr, const int* __restrict__ bexcl,
                             int* __restrict__ cursor) {
  const int g = blockIdx.x * 256 + threadIdx.x;
  if (g < N_NODES) {
    const int v = row_ptr[g] + bexcl[g >> 11];
    row_ptr[g] = v;
    cursor[g] = v;
  }
  if (g == 0) row_ptr[N_NODES] = N_EDGES;
}

__launch_bounds__(256)
__global__ void scatter_edges(const int* __restrict__ src, const int* __restrict__ dst,
                              const float* __restrict__ w, int* __restrict__ cursor,
                              int2* __restrict__ epack) {
  const int e = blockIdx.x * 256 + threadIdx.x;
  if (e >= N_EDGES) return;
  const int d = dst[e];
  const int pos = atomicAdd(&cursor[d], 1);
  epack[pos] = make_int2(src[e], __float_as_int(w[e]));
}

// ---------------- gather SpMM: H2[d] = sum w_e H1[s_e]  (wave/node, 4 slots x 16 feat)
__launch_bounds__(256)
__global__ void gather1(const int* __restrict__ row_ptr, const int2* __restrict__ epack,
                        const float* __restrict__ H1, float* __restrict__ H2) {
  const int lane = threadIdx.x & 63;
  const int node = blockIdx.x * 4 + (threadIdx.x >> 6);
  if (node >= N_NODES) return;
  const int beg = row_ptr[node], end = row_ptr[node + 1];
  const int ei = lane >> 4, f = lane & 15;
  float acc = 0.f;
  for (int k = beg + ei; k < end; k += 4) {
    const int2 p = epack[k];
    acc += __int_as_float(p.y) * H1[(size_t)p.x * HIDDEN + f];
  }
  acc += __shfl_xor(acc, 16);
  acc += __shfl_xor(acc, 32);
  if (lane < 16) H2[(size_t)node * HIDDEN + f] = acc;
}

// ---------------- gather SpMM + row softmax fused (wave/node, 2 slots x 32 classes)
__launch_bounds__(256)
__global__ void gather2_softmax(const int* __restrict__ row_ptr, const int2* __restrict__ epack,
                                const float* __restrict__ H3, float* __restrict__ O) {
  const int lane = threadIdx.x & 63;
  const int node = blockIdx.x * 4 + (threadIdx.x >> 6);
  if (node >= N_NODES) return;
  const int beg = row_ptr[node], end = row_ptr[node + 1];
  const int ei = lane >> 5, c = lane & 31;
  float acc = 0.f;
  for (int k = beg + ei; k < end; k += 2) {
    const int2 p = epack[k];
    acc += __int_as_float(p.y) * H3[(size_t)p.x * N_CLASSES + c];
  }
  acc += __shfl_xor(acc, 32);
  float m = acc;
#pragma unroll
  for (int off = 16; off >= 1; off >>= 1) m = fmaxf(m, __shfl_xor(m, off));
  const float ex = __expf(acc - m);
  float s = ex;
#pragma unroll
  for (int off = 16; off >= 1; off >>= 1) s += __shfl_xor(s, off);
  if (lane < 32) O[(size_t)node * N_CLASSES + c] = ex / s;
}

// ================= fallback (round-2) atomic SpMM path =================
__launch_bounds__(256)
__global__ void spmm1_atomic(const int* __restrict__ src, const int* __restrict__ dst,
                             const float* __restrict__ w, const float* __restrict__ H1,
                             float* __restrict__ H2) {
  const long long t = (long long)blockIdx.x * 256 + threadIdx.x;
  if (t >= (long long)N_EDGES * 4) return;
  const int e = (int)(t >> 2);
  const int q = (int)(t & 3);
  const float we = w[e];
  const float4 h = ((const float4*)(H1 + (size_t)src[e] * HIDDEN))[q];
  float* o = H2 + (size_t)dst[e] * HIDDEN + q * 4;
  unsafeAtomicAdd(o + 0, we * h.x);
  unsafeAtomicAdd(o + 1, we * h.y);
  unsafeAtomicAdd(o + 2, we * h.z);
  unsafeAtomicAdd(o + 3, we * h.w);
}

__launch_bounds__(256)
__global__ void spmm2_atomic(const int* __restrict__ src, const int* __restrict__ dst,
                             const float* __restrict__ w, const float* __restrict__ H3,
                             float* __restrict__ O) {
  const long long t = (long long)blockIdx.x * 256 + threadIdx.x;
  if (t >= (long long)N_EDGES * 8) return;
  const int e = (int)(t >> 3);
  const int q = (int)(t & 7);
  const float we = w[e];
  const float4 h = ((const float4*)(H3 + (size_t)src[e] * N_CLASSES))[q];
  float* o = O + (size_t)dst[e] * N_CLASSES + q * 4;
  unsafeAtomicAdd(o + 0, we * h.x);
  unsafeAtomicAdd(o + 1, we * h.y);
  unsafeAtomicAdd(o + 2, we * h.z);
  unsafeAtomicAdd(o + 3, we * h.w);
}

__launch_bounds__(256)
__global__ void softmax_rows(float* __restrict__ O) {
  const int n = blockIdx.x * 256 + threadIdx.x;
  if (n >= N_NODES) return;
  float4* row = (float4*)(O + (size_t)n * N_CLASSES);
  float v[N_CLASSES];
#pragma unroll
  for (int q = 0; q < N_CLASSES / 4; q++) {
    float4 t = row[q];
    v[q * 4 + 0] = t.x; v[q * 4 + 1] = t.y; v[q * 4 + 2] = t.z; v[q * 4 + 3] = t.w;
  }
  float m = v[0];
#pragma unroll
  for (int j = 1; j < N_CLASSES; j++) m = fmaxf(m, v[j]);
  float s = 0.0f;
#pragma unroll
  for (int j = 0; j < N_CLASSES; j++) { v[j] = __expf(v[j] - m); s += v[j]; }
  const float inv = 1.0f / s;
#pragma unroll
  for (int q = 0; q < N_CLASSES / 4; q++)
    row[q] = make_float4(v[q * 4] * inv, v[q * 4 + 1] * inv,
                         v[q * 4 + 2] * inv, v[q * 4 + 3] * inv);
}

// ---------------- host ----------------
extern "C" void kernel_launch(void* const* d_in, const int* in_sizes, int n_in,
                              void* d_out, int out_size, void* d_ws, size_t ws_size,
                              hipStream_t stream) {
  const float* X    = (const float*)d_in[0];
  const int*   esrc = (const int*)d_in[1];
  const int*   edst = (const int*)d_in[2];
  const float* ew   = (const float*)d_in[3];
  const float* W1   = (const float*)d_in[4];
  const float* W2   = (const float*)d_in[5];
  float* out = (float*)d_out;

  // JAX: key = random.key(42); kd1, kd2 = random.split(key)  (partitionable)
  uint32_t kd1_0, kd1_1, kd2_0, kd2_1;
  tf2x32_full(0u, 42u, 0u, 0u, &kd1_0, &kd1_1);
  tf2x32_full(0u, 42u, 0u, 1u, &kd2_0, &kd2_1);

  const int nb_nodes = (N_NODES + 255) / 256;       // 391
  const int nb_edges = (N_EDGES + 255) / 256;       // 12500
  const int nb_gather = (N_NODES + 3) / 4;          // 25000 (wave per node)
  const int nb_scan1 = (N_NODES + 2047) / 2048;     // 49

  // workspace layout (8B-aligned chunks):
  // epack[E] int2 | H1[N*16] | H2[N*16] | H3[N*32] | row_ptr[N+1 pad] | deg/cursor[N] | bsum[64] | bexcl[64]
  const size_t sz_epack = (size_t)N_EDGES * sizeof(int2);          // 25.6 MB
  const size_t sz_H1 = (size_t)N_NODES * HIDDEN * sizeof(float);   // 6.4 MB
  const size_t sz_H2 = sz_H1;                                      // 6.4 MB
  const size_t sz_H3 = (size_t)N_NODES * N_CLASSES * sizeof(float);// 12.8 MB
  const size_t sz_rp = ((size_t)(N_NODES + 1) * sizeof(int) + 7) & ~(size_t)7;
  const size_t sz_cur = (size_t)N_NODES * sizeof(int);
  const size_t sz_b = 64 * sizeof(int);
  const size_t need = sz_epack + sz_H1 + sz_H2 + sz_H3 + sz_rp + sz_cur + 2 * sz_b;

  char* p = (char*)d_ws;
  int2* epack = (int2*)p;              p += sz_epack;
  float* H1 = (float*)p;               p += sz_H1;
  float* H2 = (float*)p;               p += sz_H2;
  float* H3 = (float*)p;               p += sz_H3;
  int* row_ptr = (int*)p;              p += sz_rp;
  int* degcur = (int*)p;               p += sz_cur;   // deg, then cursor
  int* bsum = (int*)p;                 p += sz_b;
  int* bexcl = (int*)p;

  if (ws_size >= need) {
    // ---- CSR build (dst-sorted) ----
    hipMemsetAsync(degcur, 0, sz_cur, stream);
    hist_dst<<<nb_edges, 256, 0, stream>>>(edst, degcur);
    scan1<<<nb_scan1, 256, 0, stream>>>(degcur, row_ptr, bsum);
    scan2<<<1, 64, 0, stream>>>(bsum, bexcl, nb_scan1);
    scan3_cursor<<<nb_nodes, 256, 0, stream>>>(row_ptr, bexcl, degcur);
    scatter_edges<<<nb_edges, 256, 0, stream>>>(esrc, edst, ew, degcur, epack);
    // ---- pipeline ----
    gemm1_dropout<<<nb_nodes, 256, 0, stream>>>(X, W1, H1, kd1_0, kd1_1);
    gather1<<<nb_gather, 256, 0, stream>>>(row_ptr, epack, H1, H2);
    gemm2_dropout<<<nb_nodes, 256, 0, stream>>>(H2, W2, H3, kd2_0, kd2_1);
    gather2_softmax<<<nb_gather, 256, 0, stream>>>(row_ptr, epack, H3, out);
  } else {
    // fallback: round-2 atomic path (needs only H1|H2|H3 at front of ws —
    // reuse epack region as H1/H2/H3 contiguous)
    float* fH1 = (float*)d_ws;
    float* fH2 = fH1 + (size_t)N_NODES * HIDDEN;
    float* fH3 = fH2 + (size_t)N_NODES * HIDDEN;
    hipMemsetAsync(fH2, 0, sz_H2, stream);
    hipMemsetAsync(out, 0, (size_t)out_size * sizeof(float), stream);
    gemm1_dropout<<<nb_nodes, 256, 0, stream>>>(X, W1, fH1, kd1_0, kd1_1);
    spmm1_atomic<<<(N_EDGES * 4) / 256, 256, 0, stream>>>(esrc, edst, ew, fH1, fH2);
    gemm2_dropout<<<nb_nodes, 256, 0, stream>>>(fH2, W2, fH3, kd2_0, kd2_1);
    spmm2_atomic<<<(N_EDGES * 8) / 256, 256, 0, stream>>>(esrc, edst, ew, fH3, out);
    softmax_rows<<<nb_nodes, 256, 0, stream>>>(out);
  }
}